// Round 11
// baseline (901.659 us; speedup 1.0000x reference)
//
#include <hip/hip_runtime.h>
#include <hip/hip_bf16.h>

typedef unsigned short u16;
typedef unsigned int u32;
typedef __attribute__((ext_vector_type(8))) short short8;
typedef __attribute__((ext_vector_type(4))) float floatx4;

#define BB 32
#define CC 512
#define LL 16
#define DD 256
#define HH 1024
#define PP 16
#define NLAY 4

__device__ __forceinline__ float bf2f(u16 u) {
  u32 x = ((u32)u) << 16; float f; __builtin_memcpy(&f, &x, 4); return f;
}
__device__ __forceinline__ u16 f2bf(float f) {
  __hip_bfloat16 h = __float2bfloat16(f);
  u16 r; __builtin_memcpy(&r, &h, 2); return r;
}
__device__ __forceinline__ void gload_lds16(const u16* g, u16* l) {
  __builtin_amdgcn_global_load_lds(
      (const __attribute__((address_space(1))) void*)g,
      (__attribute__((address_space(3))) void*)l, 16, 0, 0);
}

// ---------------- fp32 -> bf16 conversion: 8 weight tensors + 4 embedding tables ----------------
__global__ __launch_bounds__(256) void cvt_kernel(
    const float* __restrict__ s0, const float* __restrict__ s1,
    const float* __restrict__ s2, const float* __restrict__ s3,
    const float* __restrict__ s4, const float* __restrict__ s5,
    const float* __restrict__ s6, const float* __restrict__ s7,
    const float* __restrict__ s8, const float* __restrict__ s9,
    const float* __restrict__ s10, const float* __restrict__ s11,
    u16* __restrict__ dst)
{
  const float* srcs[12] = {s0, s1, s2, s3, s4, s5, s6, s7, s8, s9, s10, s11};
  const int pfx[12] = {786432, 1048576, 2097152, 3145728, 3407872, 6553600, 7602176,
                       7618560, 7749888, 7750656, 7754752, 7885824};
  int e = (blockIdx.x * 256 + threadIdx.x) * 4;
  int seg = 0;
  while (e >= pfx[seg]) seg++;
  int start = seg ? pfx[seg - 1] : 0;
  float4 f = *(const float4*)(srcs[seg] + (e - start));
  u16 o[4] = {f2bf(f.x), f2bf(f.y), f2bf(f.z), f2bf(f.w)};
  *(uint2*)(dst + e) = *(const uint2*)o;
}

// ---------------- embed + masked mean pool (bf16 tables, 2 clauses/block, u32 loads) --------
__global__ __launch_bounds__(256) void embed_kernel(
    const int* __restrict__ vi, const int* __restrict__ si, const int* __restrict__ mk,
    const u16* __restrict__ veb, const u16* __restrict__ seb,
    const u16* __restrict__ lpeb, const u16* __restrict__ cpeb,
    u16* __restrict__ xb)
{
  int t = threadIdx.x;
  int bc = blockIdx.x * 2 + (t >> 7);
  int c = bc & (CC - 1);
  int dl = (t & 127) * 2;
  int base = bc * LL;
  float a0 = 0.f, a1 = 0.f; int cnt = 0;
  #pragma unroll
  for (int l = 0; l < LL; ++l) {
    if (mk[base + l]) {
      int v = vi[base + l], s = si[base + l];
      u32 vv = *(const u32*)&veb[v * DD + dl];
      u32 sv = *(const u32*)&seb[s * DD + dl];
      u32 lv = *(const u32*)&lpeb[l * DD + dl];
      a0 += bf2f((u16)vv) + bf2f((u16)sv) + bf2f((u16)lv);
      a1 += bf2f((u16)(vv >> 16)) + bf2f((u16)(sv >> 16)) + bf2f((u16)(lv >> 16));
      cnt++;
    }
  }
  u32 cv = *(const u32*)&cpeb[c * DD + dl];
  float inv = 1.f / (float)cnt;
  u32 pk = (u32)f2bf(a0 * inv + bf2f((u16)cv)) | ((u32)f2bf(a1 * inv + bf2f((u16)(cv >> 16))) << 16);
  *(u32*)&xb[(size_t)bc * DD + dl] = pk;
}

// ---------------- wide-N GEMM 32 rows (plain / GELU / LN-fused epilogue variants) ----------
template<int NC, bool GELU, bool LN, bool DLN>
__global__ __launch_bounds__(256) void gwide_kernel(
    const u16* __restrict__ A, const u16* __restrict__ W, const float* __restrict__ bias,
    const u16* __restrict__ resb, const float* __restrict__ gam, const float* __restrict__ bet,
    const float* __restrict__ gam2, const float* __restrict__ bet2,
    u16* __restrict__ out, int N, int K)
{
  constexpr int NT = NC / 32;
  __shared__ __align__(16) u16 As[32 * 64];
  __shared__ __align__(16) u16 Ws[NC * 64];
  __shared__ float sred[32][2][2];
  __shared__ float sred2[32][2][2];
  int t = threadIdx.x, lane = t & 63, w = t >> 6;
  int wm = w & 1, wn = w >> 1;
  int mrow = lane & 15, quad = lane >> 4;
  int bn0 = blockIdx.x * NC, bm0 = blockIdx.y * 32;

  int rA = t >> 3, gcA = (t & 7) ^ (rA & 7);
  const u16* gAp = A + (size_t)(bm0 + rA) * K + gcA * 8;
  u16* lAp = As + (w * 64) * 8;
  const u16* gW0 = W + (size_t)(bn0 + rA) * K + gcA * 8;
  u16* lW0 = Ws + (w * 64) * 8;

  floatx4 acc[NT];
  #pragma unroll
  for (int nt = 0; nt < NT; ++nt) acc[nt] = (floatx4){0.f, 0.f, 0.f, 0.f};

  for (int k0 = 0; k0 < K; k0 += 64) {
    __syncthreads();
    gload_lds16(gAp, lAp); gAp += 64;
    #pragma unroll
    for (int i = 0; i < NT; ++i)
      gload_lds16(gW0 + (size_t)i * 32 * K, lW0 + i * 2048);
    gW0 += 64;
    __syncthreads();
    #pragma unroll
    for (int ks = 0; ks < 2; ++ks) {
      int sw = ((ks * 4 + quad) ^ (mrow & 7)) * 8;
      short8 af = *(const short8*)&As[(wm * 16 + mrow) * 64 + sw];
      #pragma unroll
      for (int nt = 0; nt < NT; ++nt) {
        int rw = wn * (NC / 2) + nt * 16 + mrow;
        short8 bf = *(const short8*)&Ws[rw * 64 + sw];
        acc[nt] = __builtin_amdgcn_mfma_f32_16x16x32_bf16(af, bf, acc[nt], 0, 0, 0);
      }
    }
  }

  if constexpr (LN) {
    float val[NT][4];
    float bv[NT];
    #pragma unroll
    for (int nt = 0; nt < NT; ++nt) bv[nt] = bias[wn * 128 + nt * 16 + mrow];
    #pragma unroll
    for (int r = 0; r < 4; ++r) {
      int gm = bm0 + wm * 16 + quad * 4 + r;
      float sr = 0.f, s2r = 0.f;
      #pragma unroll
      for (int nt = 0; nt < NT; ++nt) {
        int gn = wn * 128 + nt * 16 + mrow;
        float v = acc[nt][r] + bv[nt] + bf2f(resb[(size_t)gm * 256 + gn]);
        val[nt][r] = v; sr += v; s2r += v * v;
      }
      sr += __shfl_xor(sr, 1); s2r += __shfl_xor(s2r, 1);
      sr += __shfl_xor(sr, 2); s2r += __shfl_xor(s2r, 2);
      sr += __shfl_xor(sr, 4); s2r += __shfl_xor(s2r, 4);
      sr += __shfl_xor(sr, 8); s2r += __shfl_xor(s2r, 8);
      if (mrow == 0) { sred[wm * 16 + quad * 4 + r][wn][0] = sr; sred[wm * 16 + quad * 4 + r][wn][1] = s2r; }
    }
    __syncthreads();
    #pragma unroll
    for (int r = 0; r < 4; ++r) {
      int lrow = wm * 16 + quad * 4 + r;
      float S = sred[lrow][0][0] + sred[lrow][1][0];
      float S2 = sred[lrow][0][1] + sred[lrow][1][1];
      float mean = S * (1.f / 256.f);
      float var = S2 * (1.f / 256.f) - mean * mean;
      float inv = rsqrtf(var + 1e-5f);
      float sr2 = 0.f, s2r2 = 0.f;
      #pragma unroll
      for (int nt = 0; nt < NT; ++nt) {
        int gn = wn * 128 + nt * 16 + mrow;
        float y = (val[nt][r] - mean) * inv * gam[gn] + bet[gn];
        val[nt][r] = y;
        if constexpr (DLN) { sr2 += y; s2r2 += y * y; }
        else out[(size_t)(bm0 + lrow) * 256 + gn] = f2bf(y);
      }
      if constexpr (DLN) {
        sr2 += __shfl_xor(sr2, 1); s2r2 += __shfl_xor(s2r2, 1);
        sr2 += __shfl_xor(sr2, 2); s2r2 += __shfl_xor(s2r2, 2);
        sr2 += __shfl_xor(sr2, 4); s2r2 += __shfl_xor(s2r2, 4);
        sr2 += __shfl_xor(sr2, 8); s2r2 += __shfl_xor(s2r2, 8);
        if (mrow == 0) { sred2[lrow][wn][0] = sr2; sred2[lrow][wn][1] = s2r2; }
      }
    }
    if constexpr (DLN) {
      __syncthreads();
      #pragma unroll
      for (int r = 0; r < 4; ++r) {
        int lrow = wm * 16 + quad * 4 + r;
        float S = sred2[lrow][0][0] + sred2[lrow][1][0];
        float S2 = sred2[lrow][0][1] + sred2[lrow][1][1];
        float mean = S * (1.f / 256.f);
        float var = S2 * (1.f / 256.f) - mean * mean;
        float inv = rsqrtf(var + 1e-5f);
        #pragma unroll
        for (int nt = 0; nt < NT; ++nt) {
          int gn = wn * 128 + nt * 16 + mrow;
          float z = (val[nt][r] - mean) * inv * gam2[gn] + bet2[gn];
          out[(size_t)(bm0 + lrow) * 256 + gn] = f2bf(z);
        }
      }
    }
  } else {
    #pragma unroll
    for (int nt = 0; nt < NT; ++nt) {
      int gn = bn0 + wn * (NC / 2) + nt * 16 + mrow;
      float bv = bias[gn];
      #pragma unroll
      for (int r = 0; r < 4; ++r) {
        int gm = bm0 + wm * 16 + quad * 4 + r;
        float v = acc[nt][r] + bv;
        if (GELU) v = 0.5f * v * (1.f + erff(v * 0.70710678118654752f));
        out[(size_t)gm * N + gn] = f2bf(v);
      }
    }
  }
}

// ---------------- KV GEMM, XCD-swizzled; ids 0..7 = qh tile; 32KB LDS ----------------------
__global__ __launch_bounds__(256) void gemm128s_kernel(
    const u16* __restrict__ A, const u16* __restrict__ W, const float* __restrict__ bias,
    u16* __restrict__ kb, u16* __restrict__ vtp,
    const u16* __restrict__ pqA, const u16* __restrict__ Wq, const float* __restrict__ biasq,
    u16* __restrict__ qh, int K)
{
  __shared__ __align__(16) u16 SH[16384];   // 32KB: As[0,8192) | Bs[8192,16384); V-pass tile reuses [0,8704)
  u16* As = SH;
  u16* Bs = SH + 8192;
  int t = threadIdx.x, lane = t & 63, w = t >> 6;
  int wm = w & 1, wn = w >> 1;
  int mrow = lane & 15, quad = lane >> 4;
  int id = blockIdx.x;
  int c, bm0, bn0;
  const u16* Abase; const u16* Wbase;
  if (id < 8) {
    c = -1; bm0 = 0; bn0 = id * 128;
    Abase = pqA; Wbase = Wq;
  } else {
    int id2 = id - 8;
    int g = id2 >> 6, w6 = id2 & 63;
    int r4 = (w6 & 7) >> 1;
    c = ((w6 >> 3) << 1) | (w6 & 1);
    bm0 = (g * 4 + r4) * 128;
    bn0 = c * 128;
    Abase = A; Wbase = W;
  }

  const u16* gA[4]; const u16* gB[4];
  u16* lA[4]; u16* lB[4];
  #pragma unroll
  for (int it = 0; it < 4; ++it) {
    int cc = w * 256 + it * 64 + lane;
    int r = cc >> 3;
    int gc = (cc & 7) ^ (r & 7);
    gA[it] = Abase + (size_t)(bm0 + r) * K + gc * 8;
    gB[it] = Wbase + (size_t)(bn0 + r) * K + gc * 8;
    lA[it] = As + (w * 256 + it * 64) * 8;
    lB[it] = Bs + (w * 256 + it * 64) * 8;
  }
  floatx4 acc[4][4];
  #pragma unroll
  for (int i = 0; i < 4; ++i)
    #pragma unroll
    for (int j = 0; j < 4; ++j)
      acc[i][j] = (floatx4){0.f, 0.f, 0.f, 0.f};
  int sw0 = ((0 * 4 + quad) ^ (mrow & 7)) * 8;
  int sw1 = ((1 * 4 + quad) ^ (mrow & 7)) * 8;

  for (int k0 = 0; k0 < K; k0 += 64) {
    __syncthreads();
    #pragma unroll
    for (int it = 0; it < 4; ++it) { gload_lds16(gA[it], lA[it]); gA[it] += 64; }
    #pragma unroll
    for (int it = 0; it < 4; ++it) { gload_lds16(gB[it], lB[it]); gB[it] += 64; }
    __syncthreads();
    #pragma unroll
    for (int ks = 0; ks < 2; ++ks) {
      int sw = ks ? sw1 : sw0;
      short8 af[4], bfr[4];
      #pragma unroll
      for (int mi = 0; mi < 4; ++mi)
        af[mi] = *(const short8*)&As[(wm * 64 + mi * 16 + mrow) * 64 + sw];
      #pragma unroll
      for (int nj = 0; nj < 4; ++nj)
        bfr[nj] = *(const short8*)&Bs[(wn * 64 + nj * 16 + mrow) * 64 + sw];
      #pragma unroll
      for (int mi = 0; mi < 4; ++mi)
        #pragma unroll
        for (int nj = 0; nj < 4; ++nj)
          acc[mi][nj] = __builtin_amdgcn_mfma_f32_16x16x32_bf16(af[mi], bfr[nj], acc[mi][nj], 0, 0, 0);
    }
  }

  if (c == -1) {
    if (wm == 0) {
      #pragma unroll
      for (int nj = 0; nj < 4; ++nj) {
        int gn = bn0 + wn * 64 + nj * 16 + mrow;
        float bv = biasq[gn];
        #pragma unroll
        for (int r = 0; r < 4; ++r) {
          int gm = quad * 4 + r;  // mi=0 only
          qh[(size_t)gm * 1024 + gn] = f2bf(acc[0][nj][r] + bv);
        }
      }
    }
  } else if (c < 8) {
    #pragma unroll
    for (int nj = 0; nj < 4; ++nj) {
      int gn = bn0 + wn * 64 + nj * 16 + mrow;
      float bv = bias[gn];
      #pragma unroll
      for (int mi = 0; mi < 4; ++mi)
        #pragma unroll
        for (int r = 0; r < 4; ++r) {
          int gm = bm0 + wm * 64 + mi * 16 + quad * 4 + r;
          kb[(size_t)gm * 1024 + gn] = f2bf(acc[mi][nj][r] + bv);
        }
    }
  } else {
    int h = c - 8;
    int b = bm0 >> 9, jt = (bm0 >> 7) & 3;
    size_t basev = ((size_t)(b * 8 + h) * 128) * 512 + jt * 128;
    #pragma unroll
    for (int pass = 0; pass < 2; ++pass) {
      __syncthreads();
      if (wn == pass) {
        #pragma unroll
        for (int nj = 0; nj < 4; ++nj) {
          int dl = nj * 16 + mrow;
          float bv = bias[bn0 + pass * 64 + dl];
          #pragma unroll
          for (int mi = 0; mi < 4; ++mi) {
            int jp = quad * 32 + wm * 4 + mi;
            #pragma unroll
            for (int r = 0; r < 4; ++r)
              SH[dl * 136 + jp + r * 8] = f2bf(acc[mi][nj][r] + bv);
          }
        }
      }
      __syncthreads();
      #pragma unroll
      for (int i = 0; i < 4; ++i) {
        int idx = t + i * 256;
        int d = idx >> 4, jc4 = (idx & 15) * 8;
        uint4 v = *(const uint4*)&SH[d * 136 + jc4];
        *(uint4*)(vtp + basev + (size_t)(pass * 64 + d) * 512 + jc4) = v;
      }
    }
  }
}

// ---------------- MFMA GEMM 128x128 (out-proj; flags: 1=gelu, 2=f32 out, 4=pq-broadcast res) ----
__global__ __launch_bounds__(256) void gemm128_kernel(
    const u16* __restrict__ A, const u16* __restrict__ W, const float* __restrict__ bias,
    const float* __restrict__ res, void* __restrict__ out,
    int M, int N, int K, int flags)
{
  __shared__ __align__(16) u16 As[128 * 64];
  __shared__ __align__(16) u16 Bs[128 * 64];
  int t = threadIdx.x;
  int lane = t & 63, w = t >> 6;
  int wm = w & 1, wn = w >> 1;
  int bn0 = blockIdx.x * 128, bm0 = blockIdx.y * 128;
  int mrow = lane & 15, quad = lane >> 4;

  const u16* gA[4]; const u16* gB[4];
  u16* lA[4]; u16* lB[4];
  #pragma unroll
  for (int it = 0; it < 4; ++it) {
    int c = w * 256 + it * 64 + lane;
    int r = c >> 3;
    int gc = (c & 7) ^ (r & 7);
    gA[it] = A + (size_t)(bm0 + r) * K + gc * 8;
    gB[it] = W + (size_t)(bn0 + r) * K + gc * 8;
    lA[it] = As + (w * 256 + it * 64) * 8;
    lB[it] = Bs + (w * 256 + it * 64) * 8;
  }
  floatx4 acc[4][4];
  #pragma unroll
  for (int i = 0; i < 4; ++i)
    #pragma unroll
    for (int j = 0; j < 4; ++j)
      acc[i][j] = (floatx4){0.f, 0.f, 0.f, 0.f};
  int sw0 = ((0 * 4 + quad) ^ (mrow & 7)) * 8;
  int sw1 = ((1 * 4 + quad) ^ (mrow & 7)) * 8;

  for (int k0 = 0; k0 < K; k0 += 64) {
    __syncthreads();
    #pragma unroll
    for (int it = 0; it < 4; ++it) { gload_lds16(gA[it], lA[it]); gA[it] += 64; }
    #pragma unroll
    for (int it = 0; it < 4; ++it) { gload_lds16(gB[it], lB[it]); gB[it] += 64; }
    __syncthreads();
    #pragma unroll
    for (int ks = 0; ks < 2; ++ks) {
      int sw = ks ? sw1 : sw0;
      short8 af[4], bfr[4];
      #pragma unroll
      for (int mi = 0; mi < 4; ++mi)
        af[mi] = *(const short8*)&As[(wm * 64 + mi * 16 + mrow) * 64 + sw];
      #pragma unroll
      for (int nj = 0; nj < 4; ++nj)
        bfr[nj] = *(const short8*)&Bs[(wn * 64 + nj * 16 + mrow) * 64 + sw];
      #pragma unroll
      for (int mi = 0; mi < 4; ++mi)
        #pragma unroll
        for (int nj = 0; nj < 4; ++nj)
          acc[mi][nj] = __builtin_amdgcn_mfma_f32_16x16x32_bf16(af[mi], bfr[nj], acc[mi][nj], 0, 0, 0);
    }
  }
  bool do_gelu = (flags & 1) != 0, of32 = (flags & 2) != 0;
  #pragma unroll
  for (int nj = 0; nj < 4; ++nj) {
    int gn = bn0 + wn * 64 + nj * 16 + mrow;
    float bv = bias[gn];
    #pragma unroll
    for (int mi = 0; mi < 4; ++mi) {
      #pragma unroll
      for (int r = 0; r < 4; ++r) {
        int gm = bm0 + wm * 64 + mi * 16 + quad * 4 + r;
        float v = acc[mi][nj][r] + bv;
        if (do_gelu) v = 0.5f * v * (1.f + erff(v * 0.70710678118654752f));
        if (flags & 4) v += res[(size_t)(gm & 15) * N + gn];
        else if (res) v += res[(size_t)gm * N + gn];
        if (of32) ((float*)out)[(size_t)gm * N + gn] = v;
        else      ((u16*)out)[(size_t)gm * N + gn] = f2bf(v);
      }
    }
  }
}

// ---------------- LayerNorm: one wave per row, 4 rows/block (final output) ----------------
template<int D>
__global__ __launch_bounds__(256) void lnw_kernel(
    const float* __restrict__ in, const float* __restrict__ w, const float* __restrict__ b,
    float* __restrict__ outf, u16* __restrict__ outb)
{
  constexpr int NV = D / 64;
  int lane = threadIdx.x & 63, wv = threadIdx.x >> 6;
  int row = blockIdx.x * 4 + wv;
  const float* xr = in + (size_t)row * D;
  float v[NV];
  float s = 0.f, s2 = 0.f;
  #pragma unroll
  for (int i = 0; i < NV; ++i) {
    v[i] = xr[lane + i * 64];
    s += v[i]; s2 += v[i] * v[i];
  }
  #pragma unroll
  for (int off = 32; off > 0; off >>= 1) { s += __shfl_xor(s, off); s2 += __shfl_xor(s2, off); }
  float mean = s / (float)D;
  float var = s2 / (float)D - mean * mean;
  float inv = rsqrtf(var + 1e-5f);
  #pragma unroll
  for (int i = 0; i < NV; ++i) {
    int col = lane + i * 64;
    float y = (v[i] - mean) * inv * w[col] + b[col];
    size_t o = (size_t)row * D + col;
    if (outf) outf[o] = y;
    if (outb) outb[o] = f2bf(y);
  }
}

// ---------------- encoder self-attention v4: MFMA flash-style, halved P-tile ----------------
// Pl is 16 rows/wave (mi processed sequentially; within-wave LDS RAW, DS in-order, no barrier).
// LDS: Ks 10.2K + Vt 8.7K + Pl 17.4K = 36.3KB -> 4 blocks/CU (was 53.7KB -> 2).
__global__ __launch_bounds__(256) void attn_enc4_kernel(
    const u16* __restrict__ qkv, u16* __restrict__ out)
{
  __shared__ __align__(16) u16 Ks[128 * 40];
  __shared__ __align__(16) u16 Vt[32 * 136];
  __shared__ __align__(16) u16 Pl[4 * 16 * 136];
  int qt = blockIdx.x, h = blockIdx.y, b = blockIdx.z;
  int t = threadIdx.x, lane = t & 63, w = t >> 6;
  int mrow = lane & 15, quad = lane >> 4;
  int q0 = qt * 128 + w * 32;
  short8 qf[2];
  #pragma unroll
  for (int mi = 0; mi < 2; ++mi)
    qf[mi] = *(const short8*)(qkv + (size_t)(b * CC + q0 + mi * 16 + mrow) * 768 + h * 32 + quad * 8);
  floatx4 o[2][2];
  #pragma unroll
  for (int mi = 0; mi < 2; ++mi)
    #pragma unroll
    for (int di = 0; di < 2; ++di) o[mi][di] = (floatx4){0.f, 0.f, 0.f, 0.f};
  float lst[2][4] = {{0.f,0.f,0.f,0.f},{0.f,0.f,0.f,0.f}};
  const float sc = 0.17677669529663687f * 1.4426950408889634f;
  const floatx4 zf = (floatx4){0.f, 0.f, 0.f, 0.f};
  for (int jt = 0; jt < 4; ++jt) {
    if (jt) __syncthreads();
    #pragma unroll
    for (int rep = 0; rep < 2; ++rep) {  // K tile: 128 j x 32 d
      int j = (t >> 2) + rep * 64;
      int q4 = (t & 3) * 8;
      uint4 kk = *(const uint4*)(qkv + (size_t)(b * CC + jt * 128 + j) * 768 + 256 + h * 32 + q4);
      *(uint4*)&Ks[j * 40 + q4] = kk;
    }
    #pragma unroll
    for (int rep = 0; rep < 2; ++rep) {  // V tile: transpose+permute into Vt[d][jp]
      int jl = (t >> 2) + rep * 64;
      int d0 = (t & 3) * 8;
      uint4 vv = *(const uint4*)(qkv + (size_t)(b * CC + jt * 128 + jl) * 768 + 512 + h * 32 + d0);
      u16 tmp[8]; *(uint4*)tmp = vv;
      int jp = (jl & 15) * 8 + (jl >> 4);
      #pragma unroll
      for (int i = 0; i < 8; ++i) Vt[(d0 + i) * 136 + jp] = tmp[i];
    }
    __syncthreads();
    floatx4 s[2][8];
    #pragma unroll
    for (int nj = 0; nj < 8; ++nj) {
      short8 bf = *(const short8*)&Ks[(nj * 16 + mrow) * 40 + quad * 8];
      s[0][nj] = __builtin_amdgcn_mfma_f32_16x16x32_bf16(qf[0], bf, zf, 0, 0, 0);
      s[1][nj] = __builtin_amdgcn_mfma_f32_16x16x32_bf16(qf[1], bf, zf, 0, 0, 0);
    }
    #pragma unroll
    for (int mi = 0; mi < 2; ++mi) {
      #pragma unroll
      for (int r = 0; r < 4; ++r) {
        float ps = 0.f; u16 hv[8];
        #pragma unroll
        for (int nj = 0; nj < 8; ++nj) {
          float p = exp2f(s[mi][nj][r] * sc);
          ps += p; hv[nj] = f2bf(p);
        }
        lst[mi][r] += ps;
        *(uint4*)&Pl[(w * 16 + quad * 4 + r) * 136 + mrow * 8] = *(uint4*)hv;
      }
      #pragma unroll
      for (int ks = 0; ks < 4; ++ks) {
        short8 pa = *(const short8*)&Pl[(w * 16 + mrow) * 136 + ks * 32 + quad * 8];
        short8 b0 = *(const short8*)&Vt[mrow * 136 + ks * 32 + quad * 8];
        short8 b1 = *(const short8*)&Vt[(16 + mrow) * 136 + ks * 32 + quad * 8];
        o[mi][0] = __builtin_amdgcn_mfma_f32_16x16x32_bf16(pa, b0, o[mi][0], 0, 0, 0);
        o[mi][1] = __builtin_amdgcn_mfma_f32_16x16x32_bf16(pa, b1, o[mi][1], 0, 0, 0);
      }
    }
  }
  #pragma unroll
  for (int mi = 0; mi < 2; ++mi) {
    #pragma unroll
    for (int r = 0; r < 4; ++r) {
      float l = lst[mi][r];
      l += __shfl_xor(l, 1); l += __shfl_xor(l, 2);
      l += __shfl_xor(l, 4); l += __shfl_xor(l, 8);
      float inv = 1.f / l;
      int row = b * CC + q0 + mi * 16 + quad * 4 + r;
      #pragma unroll
      for (int di = 0; di < 2; ++di)
        out[(size_t)row * DD + h * 32 + di * 16 + mrow] = f2bf(o[mi][di][r] * inv);
    }
  }
}

// ---------------- prefix cross-attention: MFMA ----------------
__global__ __launch_bounds__(256) void attn_pref2_kernel(
    const u16* __restrict__ qh, const u16* __restrict__ kb, const u16* __restrict__ vtp,
    u16* __restrict__ out)
{
  __shared__ __align__(16) u16 Pl[4 * 16 * 136];
  __shared__ float Ored[4 * 16 * 128];
  __shared__ float Lred[4 * 16];
  int h = blockIdx.x, b = blockIdx.y;
  int t = threadIdx.x, lane = t & 63, w = t >> 6;
  int mrow = lane & 15, quad = lane >> 4;
  const float sc = 0.08838834764831845f * 1.4426950408889634f;
  const floatx4 zf = (floatx4){0.f, 0.f, 0.f, 0.f};
  short8 qf[4];
  #pragma unroll
  for (int ks = 0; ks < 4; ++ks)
    qf[ks] = *(const short8*)(qh + mrow * HH + h * 128 + ks * 32 + quad * 8);
  const u16* kbase = kb + ((size_t)(b * CC + w * 128)) * 1024 + h * 128;
  floatx4 s[8];
  #pragma unroll
  for (int nj = 0; nj < 8; ++nj) {
    floatx4 a = zf;
    #pragma unroll
    for (int ks = 0; ks < 4; ++ks) {
      short8 kf = *(const short8*)(kbase + (size_t)(nj * 16 + mrow) * 1024 + ks * 32 + quad * 8);
      a = __builtin_amdgcn_mfma_f32_16x16x32_bf16(qf[ks], kf, a, 0, 0, 0);
    }
    s[nj] = a;
  }
  #pragma unroll
  for (int r = 0; r < 4; ++r) {
    float ps = 0.f; u16 hv[8];
    #pragma unroll
    for (int nj = 0; nj < 8; ++nj) {
      float p = exp2f(s[nj][r] * sc);
      ps += p; hv[nj] = f2bf(p);
    }
    ps += __shfl_xor(ps, 1); ps += __shfl_xor(ps, 2);
    ps += __shfl_xor(ps, 4); ps += __shfl_xor(ps, 8);
    if (mrow == 0) Lred[w * 16 + quad * 4 + r] = ps;
    *(uint4*)&Pl[(w * 16 + quad * 4 + r) * 136 + mrow * 8] = *(uint4*)hv;
  }
  short8 pa[4];
  #pragma unroll
  for (int ks = 0; ks < 4; ++ks)
    pa[ks] = *(const short8*)&Pl[(w * 16 + mrow) * 136 + ks * 32 + quad * 8];
  const u16* vbase = vtp + ((size_t)(b * 8 + h) * 128) * 512 + w * 128;
  floatx4 o[8];
  #pragma unroll
  for (int nd = 0; nd < 8; ++nd) o[nd] = zf;
  #pragma unroll
  for (int nd = 0; nd < 8; ++nd) {
    #pragma unroll
    for (int ks = 0; ks < 4; ++ks) {
      short8 vf = *(const short8*)(vbase + (size_t)(nd * 16 + mrow) * 512 + ks * 32 + quad * 8);
      o[nd] = __builtin_amdgcn_mfma_f32_16x16x32_bf16(pa[ks], vf, o[nd], 0, 0, 0);
    }
  }
  #pragma unroll
  for (int nd = 0; nd < 8; ++nd)
    #pragma unroll
    for (int r = 0; r < 4; ++r)
      Ored[(w * 16 + quad * 4 + r) * 128 + nd * 16 + mrow] = o[nd][r];
  __syncthreads();
  int row = t >> 4, d0 = (t & 15) * 8;
  float l = Lred[row] + Lred[16 + row] + Lred[32 + row] + Lred[48 + row];
  float inv = 1.f / l;
  u16 ov[8];
  #pragma unroll
  for (int i = 0; i < 8; ++i) {
    int d = d0 + i;
    float sum = Ored[row * 128 + d] + Ored[(16 + row) * 128 + d]
              + Ored[(32 + row) * 128 + d] + Ored[(48 + row) * 128 + d];
    ov[i] = f2bf(sum * inv);
  }
  *(uint4*)(out + ((size_t)(b * PP + row)) * HH + h * 128 + d0) = *(const uint4*)ov;
}

extern "C" void kernel_launch(void* const* d_in, const int* in_sizes, int n_in,
                              void* d_out, int out_size, void* d_ws, size_t ws_size,
                              hipStream_t stream)
{
  const int* vi = (const int*)d_in[0];
  const int* si = (const int*)d_in[1];
  const int* mk = (const int*)d_in[2];
  const float* ve   = (const float*)d_in[3];
  const float* se   = (const float*)d_in[4];
  const float* lpe  = (const float*)d_in[5];
  const float* cpe  = (const float*)d_in[6];
  const float* eiw  = (const float*)d_in[7];
  const float* eib  = (const float*)d_in[8];
  const float* eow  = (const float*)d_in[9];
  const float* eob  = (const float*)d_in[10];
  const float* f1w  = (const float*)d_in[11];
  const float* f1b  = (const float*)d_in[12];
  const float* f2w  = (const float*)d_in[13];
  const float* f2b  = (const float*)d_in[14];
  const float* n1w  = (const float*)d_in[15];
  const float* n1b  = (const float*)d_in[16];
  const float* n2w  = (const float*)d_in[17];
  const float* n2b  = (const float*)d_in[18];
  const float* tlw  = (const float*)d_in[19];
  const float* tlb  = (const float*)d_in[20];
  const float* thw  = (const float*)d_in[21];
  const float* thb  = (const float*)d_in[22];
  const float* pq   = (const float*)d_in[23];
  const float* paiw = (const float*)d_in[24];
  const float* paib = (const float*)d_in[25];
  const float* paow = (const float*)d_in[26];
  const float* paob = (const float*)d_in[27];
  const float* pnw  = (const float*)d_in[28];
  const float* pnb  = (const float*)d_in[29];

  const int NROW = BB * CC;  // 16384
  const size_t MB = 1048576;
  char* base = (char*)d_ws;
  // encoder phase:
  u16* xb   = (u16*)(base);                // [0,8M)   bf16 residual stream (post-LN)
  u16* qkvb = (u16*)(base + 8 * MB);       // [8M,32M)
  u16* atto = (u16*)(base + 32 * MB);      // [32M,40M)
  u16* h1   = (u16*)(base + 8 * MB);       // [8M,40M) (qkvb/atto dead)
  u16* tln  = (u16*)(base + 96 * MB);      // [96M,104M)
  // final phase:
  u16* ch   = (u16*)(base);                // [0,32M)   (xb/h1 dead)
  u16* kb   = (u16*)(base + 32 * MB);      // [32M,64M)
  u16* vtp  = (u16*)(base + 64 * MB);      // [64M,96M)
  u16* wbf  = (u16*)(base + 104 * MB);     // [104M,~119.8M)
  u16* qh    = (u16*)(base + 120 * MB);
  u16* prefo = qh + 32768;
  float* prefout = (float*)(base + 122 * MB);

  u16* eiw_b  = wbf + 0;
  u16* eow_b  = wbf + 786432;
  u16* f1w_b  = wbf + 1048576;
  u16* f2w_b  = wbf + 2097152;
  u16* thw_b  = wbf + 3145728;
  u16* paiw_b = wbf + 3407872;
  u16* paow_b = wbf + 6553600;
  u16* pqb    = wbf + 7602176;
  u16* veb    = wbf + 7618560;
  u16* seb    = wbf + 7749888;
  u16* lpeb   = wbf + 7750656;
  u16* cpeb   = wbf + 7754752;

  dim3 blk(256);
  cvt_kernel<<<7701, blk, 0, stream>>>(eiw, eow, f1w, f2w, thw, paiw, paow, pq,
                                       ve, se, lpe, cpe, wbf);
  embed_kernel<<<NROW/2, blk, 0, stream>>>(vi, si, mk, veb, seb, lpeb, cpeb, xb);
  for (int i = 0; i < NLAY; ++i) {
    gwide_kernel<384, false, false, false><<<dim3(2, NROW/32), blk, 0, stream>>>(
        xb, eiw_b + (size_t)i*768*DD, eib + i*768, nullptr, nullptr, nullptr, nullptr, nullptr,
        qkvb, 768, DD);
    attn_enc4_kernel<<<dim3(4, 8, BB), blk, 0, stream>>>(qkvb, atto);
    gwide_kernel<256, false, true, false><<<dim3(1, NROW/32), blk, 0, stream>>>(
        atto, eow_b + (size_t)i*DD*DD, eob + i*DD, xb, n1w + i*DD, n1b + i*DD, nullptr, nullptr,
        xb, DD, DD);
    gwide_kernel<256, true, false, false><<<dim3(4, NROW/32), blk, 0, stream>>>(
        xb, f1w_b + (size_t)i*HH*DD, f1b + i*HH, nullptr, nullptr, nullptr, nullptr, nullptr,
        h1, HH, DD);
    if (i < NLAY - 1) {
      gwide_kernel<256, false, true, false><<<dim3(1, NROW/32), blk, 0, stream>>>(
          h1, f2w_b + (size_t)i*DD*HH, f2b + i*DD, xb, n2w + i*DD, n2b + i*DD, nullptr, nullptr,
          xb, DD, HH);
    } else {
      gwide_kernel<256, false, true, true><<<dim3(1, NROW/32), blk, 0, stream>>>(
          h1, f2w_b + (size_t)i*DD*HH, f2b + i*DD, xb, n2w + i*DD, n2b + i*DD, tlw, tlb,
          tln, DD, HH);
    }
  }
  gwide_kernel<256, false, false, false><<<dim3(4, NROW/32), blk, 0, stream>>>(
      tln, thw_b, thb, nullptr, nullptr, nullptr, nullptr, nullptr, ch, HH, DD);
  gemm128s_kernel<<<2056, blk, 0, stream>>>(
      ch, paiw_b + (size_t)HH*HH, paib + HH, kb, vtp,
      pqb, paiw_b, paib, qh, HH);
  attn_pref2_kernel<<<dim3(8, BB), blk, 0, stream>>>(qh, kb, vtp, prefo);
  gemm128_kernel<<<dim3(1024/128, (BB*PP)/128), blk, 0, stream>>>(
      prefo, paow_b, paob, pq, prefout, BB*PP, HH, HH, 2 | 4);
  lnw_kernel<1024><<<(BB*PP)/4, blk, 0, stream>>>(prefout, pnw, pnb, (float*)d_out, nullptr);
}

// Round 12
// 796.930 us; speedup vs baseline: 1.1314x; 1.1314x over previous
//
#include <hip/hip_runtime.h>
#include <hip/hip_bf16.h>

typedef unsigned short u16;
typedef unsigned int u32;
typedef __attribute__((ext_vector_type(8))) short short8;
typedef __attribute__((ext_vector_type(4))) float floatx4;

#define BB 32
#define CC 512
#define LL 16
#define DD 256
#define HH 1024
#define PP 16
#define NLAY 4

__device__ __forceinline__ float bf2f(u16 u) {
  u32 x = ((u32)u) << 16; float f; __builtin_memcpy(&f, &x, 4); return f;
}
__device__ __forceinline__ u16 f2bf(float f) {
  __hip_bfloat16 h = __float2bfloat16(f);
  u16 r; __builtin_memcpy(&r, &h, 2); return r;
}
__device__ __forceinline__ void gload_lds16(const u16* g, u16* l) {
  __builtin_amdgcn_global_load_lds(
      (const __attribute__((address_space(1))) void*)g,
      (__attribute__((address_space(3))) void*)l, 16, 0, 0);
}

// ---------------- fp32 -> bf16 conversion: 8 weight tensors + 4 embedding tables ----------------
__global__ __launch_bounds__(256) void cvt_kernel(
    const float* __restrict__ s0, const float* __restrict__ s1,
    const float* __restrict__ s2, const float* __restrict__ s3,
    const float* __restrict__ s4, const float* __restrict__ s5,
    const float* __restrict__ s6, const float* __restrict__ s7,
    const float* __restrict__ s8, const float* __restrict__ s9,
    const float* __restrict__ s10, const float* __restrict__ s11,
    u16* __restrict__ dst)
{
  const float* srcs[12] = {s0, s1, s2, s3, s4, s5, s6, s7, s8, s9, s10, s11};
  const int pfx[12] = {786432, 1048576, 2097152, 3145728, 3407872, 6553600, 7602176,
                       7618560, 7749888, 7750656, 7754752, 7885824};
  int e = (blockIdx.x * 256 + threadIdx.x) * 4;
  int seg = 0;
  while (e >= pfx[seg]) seg++;
  int start = seg ? pfx[seg - 1] : 0;
  float4 f = *(const float4*)(srcs[seg] + (e - start));
  u16 o[4] = {f2bf(f.x), f2bf(f.y), f2bf(f.z), f2bf(f.w)};
  *(uint2*)(dst + e) = *(const uint2*)o;
}

// ---------------- embed + masked mean pool (bf16 tables, 2 clauses/block, u32 loads) --------
__global__ __launch_bounds__(256) void embed_kernel(
    const int* __restrict__ vi, const int* __restrict__ si, const int* __restrict__ mk,
    const u16* __restrict__ veb, const u16* __restrict__ seb,
    const u16* __restrict__ lpeb, const u16* __restrict__ cpeb,
    u16* __restrict__ xb)
{
  int t = threadIdx.x;
  int bc = blockIdx.x * 2 + (t >> 7);
  int c = bc & (CC - 1);
  int dl = (t & 127) * 2;
  int base = bc * LL;
  float a0 = 0.f, a1 = 0.f; int cnt = 0;
  #pragma unroll
  for (int l = 0; l < LL; ++l) {
    if (mk[base + l]) {
      int v = vi[base + l], s = si[base + l];
      u32 vv = *(const u32*)&veb[v * DD + dl];
      u32 sv = *(const u32*)&seb[s * DD + dl];
      u32 lv = *(const u32*)&lpeb[l * DD + dl];
      a0 += bf2f((u16)vv) + bf2f((u16)sv) + bf2f((u16)lv);
      a1 += bf2f((u16)(vv >> 16)) + bf2f((u16)(sv >> 16)) + bf2f((u16)(lv >> 16));
      cnt++;
    }
  }
  u32 cv = *(const u32*)&cpeb[c * DD + dl];
  float inv = 1.f / (float)cnt;
  u32 pk = (u32)f2bf(a0 * inv + bf2f((u16)cv)) | ((u32)f2bf(a1 * inv + bf2f((u16)(cv >> 16))) << 16);
  *(u32*)&xb[(size_t)bc * DD + dl] = pk;
}

// ---------------- wide-N GEMM 32 rows (plain / GELU / LN-fused epilogue variants) ----------
template<int NC, bool GELU, bool LN, bool DLN>
__global__ __launch_bounds__(256) void gwide_kernel(
    const u16* __restrict__ A, const u16* __restrict__ W, const float* __restrict__ bias,
    const u16* __restrict__ resb, const float* __restrict__ gam, const float* __restrict__ bet,
    const float* __restrict__ gam2, const float* __restrict__ bet2,
    u16* __restrict__ out, int N, int K)
{
  constexpr int NT = NC / 32;
  __shared__ __align__(16) u16 As[32 * 64];
  __shared__ __align__(16) u16 Ws[NC * 64];
  __shared__ float sred[32][2][2];
  __shared__ float sred2[32][2][2];
  int t = threadIdx.x, lane = t & 63, w = t >> 6;
  int wm = w & 1, wn = w >> 1;
  int mrow = lane & 15, quad = lane >> 4;
  int bn0 = blockIdx.x * NC, bm0 = blockIdx.y * 32;

  int rA = t >> 3, gcA = (t & 7) ^ (rA & 7);
  const u16* gAp = A + (size_t)(bm0 + rA) * K + gcA * 8;
  u16* lAp = As + (w * 64) * 8;
  const u16* gW0 = W + (size_t)(bn0 + rA) * K + gcA * 8;
  u16* lW0 = Ws + (w * 64) * 8;

  floatx4 acc[NT];
  #pragma unroll
  for (int nt = 0; nt < NT; ++nt) acc[nt] = (floatx4){0.f, 0.f, 0.f, 0.f};

  for (int k0 = 0; k0 < K; k0 += 64) {
    __syncthreads();
    gload_lds16(gAp, lAp); gAp += 64;
    #pragma unroll
    for (int i = 0; i < NT; ++i)
      gload_lds16(gW0 + (size_t)i * 32 * K, lW0 + i * 2048);
    gW0 += 64;
    __syncthreads();
    #pragma unroll
    for (int ks = 0; ks < 2; ++ks) {
      int sw = ((ks * 4 + quad) ^ (mrow & 7)) * 8;
      short8 af = *(const short8*)&As[(wm * 16 + mrow) * 64 + sw];
      #pragma unroll
      for (int nt = 0; nt < NT; ++nt) {
        int rw = wn * (NC / 2) + nt * 16 + mrow;
        short8 bf = *(const short8*)&Ws[rw * 64 + sw];
        acc[nt] = __builtin_amdgcn_mfma_f32_16x16x32_bf16(af, bf, acc[nt], 0, 0, 0);
      }
    }
  }

  if constexpr (LN) {
    float val[NT][4];
    float bv[NT];
    #pragma unroll
    for (int nt = 0; nt < NT; ++nt) bv[nt] = bias[wn * 128 + nt * 16 + mrow];
    #pragma unroll
    for (int r = 0; r < 4; ++r) {
      int gm = bm0 + wm * 16 + quad * 4 + r;
      float sr = 0.f, s2r = 0.f;
      #pragma unroll
      for (int nt = 0; nt < NT; ++nt) {
        int gn = wn * 128 + nt * 16 + mrow;
        float v = acc[nt][r] + bv[nt] + bf2f(resb[(size_t)gm * 256 + gn]);
        val[nt][r] = v; sr += v; s2r += v * v;
      }
      sr += __shfl_xor(sr, 1); s2r += __shfl_xor(s2r, 1);
      sr += __shfl_xor(sr, 2); s2r += __shfl_xor(s2r, 2);
      sr += __shfl_xor(sr, 4); s2r += __shfl_xor(s2r, 4);
      sr += __shfl_xor(sr, 8); s2r += __shfl_xor(s2r, 8);
      if (mrow == 0) { sred[wm * 16 + quad * 4 + r][wn][0] = sr; sred[wm * 16 + quad * 4 + r][wn][1] = s2r; }
    }
    __syncthreads();
    #pragma unroll
    for (int r = 0; r < 4; ++r) {
      int lrow = wm * 16 + quad * 4 + r;
      float S = sred[lrow][0][0] + sred[lrow][1][0];
      float S2 = sred[lrow][0][1] + sred[lrow][1][1];
      float mean = S * (1.f / 256.f);
      float var = S2 * (1.f / 256.f) - mean * mean;
      float inv = rsqrtf(var + 1e-5f);
      float sr2 = 0.f, s2r2 = 0.f;
      #pragma unroll
      for (int nt = 0; nt < NT; ++nt) {
        int gn = wn * 128 + nt * 16 + mrow;
        float y = (val[nt][r] - mean) * inv * gam[gn] + bet[gn];
        val[nt][r] = y;
        if constexpr (DLN) { sr2 += y; s2r2 += y * y; }
        else out[(size_t)(bm0 + lrow) * 256 + gn] = f2bf(y);
      }
      if constexpr (DLN) {
        sr2 += __shfl_xor(sr2, 1); s2r2 += __shfl_xor(s2r2, 1);
        sr2 += __shfl_xor(sr2, 2); s2r2 += __shfl_xor(s2r2, 2);
        sr2 += __shfl_xor(sr2, 4); s2r2 += __shfl_xor(s2r2, 4);
        sr2 += __shfl_xor(sr2, 8); s2r2 += __shfl_xor(s2r2, 8);
        if (mrow == 0) { sred2[lrow][wn][0] = sr2; sred2[lrow][wn][1] = s2r2; }
      }
    }
    if constexpr (DLN) {
      __syncthreads();
      #pragma unroll
      for (int r = 0; r < 4; ++r) {
        int lrow = wm * 16 + quad * 4 + r;
        float S = sred2[lrow][0][0] + sred2[lrow][1][0];
        float S2 = sred2[lrow][0][1] + sred2[lrow][1][1];
        float mean = S * (1.f / 256.f);
        float var = S2 * (1.f / 256.f) - mean * mean;
        float inv = rsqrtf(var + 1e-5f);
        #pragma unroll
        for (int nt = 0; nt < NT; ++nt) {
          int gn = wn * 128 + nt * 16 + mrow;
          float z = (val[nt][r] - mean) * inv * gam2[gn] + bet2[gn];
          out[(size_t)(bm0 + lrow) * 256 + gn] = f2bf(z);
        }
      }
    }
  } else {
    #pragma unroll
    for (int nt = 0; nt < NT; ++nt) {
      int gn = bn0 + wn * (NC / 2) + nt * 16 + mrow;
      float bv = bias[gn];
      #pragma unroll
      for (int r = 0; r < 4; ++r) {
        int gm = bm0 + wm * 16 + quad * 4 + r;
        float v = acc[nt][r] + bv;
        if (GELU) v = 0.5f * v * (1.f + erff(v * 0.70710678118654752f));
        out[(size_t)gm * N + gn] = f2bf(v);
      }
    }
  }
}

// ---------------- KV GEMM, XCD-swizzled; ids 0..7 = qh tile; 32KB LDS ----------------------
__global__ __launch_bounds__(256) void gemm128s_kernel(
    const u16* __restrict__ A, const u16* __restrict__ W, const float* __restrict__ bias,
    u16* __restrict__ kb, u16* __restrict__ vtp,
    const u16* __restrict__ pqA, const u16* __restrict__ Wq, const float* __restrict__ biasq,
    u16* __restrict__ qh, int K)
{
  __shared__ __align__(16) u16 SH[16384];   // 32KB: As[0,8192) | Bs[8192,16384); V-pass tile reuses [0,8704)
  u16* As = SH;
  u16* Bs = SH + 8192;
  int t = threadIdx.x, lane = t & 63, w = t >> 6;
  int wm = w & 1, wn = w >> 1;
  int mrow = lane & 15, quad = lane >> 4;
  int id = blockIdx.x;
  int c, bm0, bn0;
  const u16* Abase; const u16* Wbase;
  if (id < 8) {
    c = -1; bm0 = 0; bn0 = id * 128;
    Abase = pqA; Wbase = Wq;
  } else {
    int id2 = id - 8;
    int g = id2 >> 6, w6 = id2 & 63;
    int r4 = (w6 & 7) >> 1;
    c = ((w6 >> 3) << 1) | (w6 & 1);
    bm0 = (g * 4 + r4) * 128;
    bn0 = c * 128;
    Abase = A; Wbase = W;
  }

  const u16* gA[4]; const u16* gB[4];
  u16* lA[4]; u16* lB[4];
  #pragma unroll
  for (int it = 0; it < 4; ++it) {
    int cc = w * 256 + it * 64 + lane;
    int r = cc >> 3;
    int gc = (cc & 7) ^ (r & 7);
    gA[it] = Abase + (size_t)(bm0 + r) * K + gc * 8;
    gB[it] = Wbase + (size_t)(bn0 + r) * K + gc * 8;
    lA[it] = As + (w * 256 + it * 64) * 8;
    lB[it] = Bs + (w * 256 + it * 64) * 8;
  }
  floatx4 acc[4][4];
  #pragma unroll
  for (int i = 0; i < 4; ++i)
    #pragma unroll
    for (int j = 0; j < 4; ++j)
      acc[i][j] = (floatx4){0.f, 0.f, 0.f, 0.f};
  int sw0 = ((0 * 4 + quad) ^ (mrow & 7)) * 8;
  int sw1 = ((1 * 4 + quad) ^ (mrow & 7)) * 8;

  for (int k0 = 0; k0 < K; k0 += 64) {
    __syncthreads();
    #pragma unroll
    for (int it = 0; it < 4; ++it) { gload_lds16(gA[it], lA[it]); gA[it] += 64; }
    #pragma unroll
    for (int it = 0; it < 4; ++it) { gload_lds16(gB[it], lB[it]); gB[it] += 64; }
    __syncthreads();
    #pragma unroll
    for (int ks = 0; ks < 2; ++ks) {
      int sw = ks ? sw1 : sw0;
      short8 af[4], bfr[4];
      #pragma unroll
      for (int mi = 0; mi < 4; ++mi)
        af[mi] = *(const short8*)&As[(wm * 64 + mi * 16 + mrow) * 64 + sw];
      #pragma unroll
      for (int nj = 0; nj < 4; ++nj)
        bfr[nj] = *(const short8*)&Bs[(wn * 64 + nj * 16 + mrow) * 64 + sw];
      #pragma unroll
      for (int mi = 0; mi < 4; ++mi)
        #pragma unroll
        for (int nj = 0; nj < 4; ++nj)
          acc[mi][nj] = __builtin_amdgcn_mfma_f32_16x16x32_bf16(af[mi], bfr[nj], acc[mi][nj], 0, 0, 0);
    }
  }

  if (c == -1) {
    if (wm == 0) {
      #pragma unroll
      for (int nj = 0; nj < 4; ++nj) {
        int gn = bn0 + wn * 64 + nj * 16 + mrow;
        float bv = biasq[gn];
        #pragma unroll
        for (int r = 0; r < 4; ++r) {
          int gm = quad * 4 + r;  // mi=0 only
          qh[(size_t)gm * 1024 + gn] = f2bf(acc[0][nj][r] + bv);
        }
      }
    }
  } else if (c < 8) {
    #pragma unroll
    for (int nj = 0; nj < 4; ++nj) {
      int gn = bn0 + wn * 64 + nj * 16 + mrow;
      float bv = bias[gn];
      #pragma unroll
      for (int mi = 0; mi < 4; ++mi)
        #pragma unroll
        for (int r = 0; r < 4; ++r) {
          int gm = bm0 + wm * 64 + mi * 16 + quad * 4 + r;
          kb[(size_t)gm * 1024 + gn] = f2bf(acc[mi][nj][r] + bv);
        }
    }
  } else {
    int h = c - 8;
    int b = bm0 >> 9, jt = (bm0 >> 7) & 3;
    size_t basev = ((size_t)(b * 8 + h) * 128) * 512 + jt * 128;
    #pragma unroll
    for (int pass = 0; pass < 2; ++pass) {
      __syncthreads();
      if (wn == pass) {
        #pragma unroll
        for (int nj = 0; nj < 4; ++nj) {
          int dl = nj * 16 + mrow;
          float bv = bias[bn0 + pass * 64 + dl];
          #pragma unroll
          for (int mi = 0; mi < 4; ++mi) {
            int jp = quad * 32 + wm * 4 + mi;
            #pragma unroll
            for (int r = 0; r < 4; ++r)
              SH[dl * 136 + jp + r * 8] = f2bf(acc[mi][nj][r] + bv);
          }
        }
      }
      __syncthreads();
      #pragma unroll
      for (int i = 0; i < 4; ++i) {
        int idx = t + i * 256;
        int d = idx >> 4, jc4 = (idx & 15) * 8;
        uint4 v = *(const uint4*)&SH[d * 136 + jc4];
        *(uint4*)(vtp + basev + (size_t)(pass * 64 + d) * 512 + jc4) = v;
      }
    }
  }
}

// ---------------- MFMA GEMM 128x128 (out-proj; flags: 1=gelu, 2=f32 out, 4=pq-broadcast res) ----
__global__ __launch_bounds__(256) void gemm128_kernel(
    const u16* __restrict__ A, const u16* __restrict__ W, const float* __restrict__ bias,
    const float* __restrict__ res, void* __restrict__ out,
    int M, int N, int K, int flags)
{
  __shared__ __align__(16) u16 As[128 * 64];
  __shared__ __align__(16) u16 Bs[128 * 64];
  int t = threadIdx.x;
  int lane = t & 63, w = t >> 6;
  int wm = w & 1, wn = w >> 1;
  int bn0 = blockIdx.x * 128, bm0 = blockIdx.y * 128;
  int mrow = lane & 15, quad = lane >> 4;

  const u16* gA[4]; const u16* gB[4];
  u16* lA[4]; u16* lB[4];
  #pragma unroll
  for (int it = 0; it < 4; ++it) {
    int c = w * 256 + it * 64 + lane;
    int r = c >> 3;
    int gc = (c & 7) ^ (r & 7);
    gA[it] = A + (size_t)(bm0 + r) * K + gc * 8;
    gB[it] = W + (size_t)(bn0 + r) * K + gc * 8;
    lA[it] = As + (w * 256 + it * 64) * 8;
    lB[it] = Bs + (w * 256 + it * 64) * 8;
  }
  floatx4 acc[4][4];
  #pragma unroll
  for (int i = 0; i < 4; ++i)
    #pragma unroll
    for (int j = 0; j < 4; ++j)
      acc[i][j] = (floatx4){0.f, 0.f, 0.f, 0.f};
  int sw0 = ((0 * 4 + quad) ^ (mrow & 7)) * 8;
  int sw1 = ((1 * 4 + quad) ^ (mrow & 7)) * 8;

  for (int k0 = 0; k0 < K; k0 += 64) {
    __syncthreads();
    #pragma unroll
    for (int it = 0; it < 4; ++it) { gload_lds16(gA[it], lA[it]); gA[it] += 64; }
    #pragma unroll
    for (int it = 0; it < 4; ++it) { gload_lds16(gB[it], lB[it]); gB[it] += 64; }
    __syncthreads();
    #pragma unroll
    for (int ks = 0; ks < 2; ++ks) {
      int sw = ks ? sw1 : sw0;
      short8 af[4], bfr[4];
      #pragma unroll
      for (int mi = 0; mi < 4; ++mi)
        af[mi] = *(const short8*)&As[(wm * 64 + mi * 16 + mrow) * 64 + sw];
      #pragma unroll
      for (int nj = 0; nj < 4; ++nj)
        bfr[nj] = *(const short8*)&Bs[(wn * 64 + nj * 16 + mrow) * 64 + sw];
      #pragma unroll
      for (int mi = 0; mi < 4; ++mi)
        #pragma unroll
        for (int nj = 0; nj < 4; ++nj)
          acc[mi][nj] = __builtin_amdgcn_mfma_f32_16x16x32_bf16(af[mi], bfr[nj], acc[mi][nj], 0, 0, 0);
    }
  }
  bool do_gelu = (flags & 1) != 0, of32 = (flags & 2) != 0;
  #pragma unroll
  for (int nj = 0; nj < 4; ++nj) {
    int gn = bn0 + wn * 64 + nj * 16 + mrow;
    float bv = bias[gn];
    #pragma unroll
    for (int mi = 0; mi < 4; ++mi) {
      #pragma unroll
      for (int r = 0; r < 4; ++r) {
        int gm = bm0 + wm * 64 + mi * 16 + quad * 4 + r;
        float v = acc[mi][nj][r] + bv;
        if (do_gelu) v = 0.5f * v * (1.f + erff(v * 0.70710678118654752f));
        if (flags & 4) v += res[(size_t)(gm & 15) * N + gn];
        else if (res) v += res[(size_t)gm * N + gn];
        if (of32) ((float*)out)[(size_t)gm * N + gn] = v;
        else      ((u16*)out)[(size_t)gm * N + gn] = f2bf(v);
      }
    }
  }
}

// ---------------- LayerNorm: one wave per row, 4 rows/block (final output) ----------------
template<int D>
__global__ __launch_bounds__(256) void lnw_kernel(
    const float* __restrict__ in, const float* __restrict__ w, const float* __restrict__ b,
    float* __restrict__ outf, u16* __restrict__ outb)
{
  constexpr int NV = D / 64;
  int lane = threadIdx.x & 63, wv = threadIdx.x >> 6;
  int row = blockIdx.x * 4 + wv;
  const float* xr = in + (size_t)row * D;
  float v[NV];
  float s = 0.f, s2 = 0.f;
  #pragma unroll
  for (int i = 0; i < NV; ++i) {
    v[i] = xr[lane + i * 64];
    s += v[i]; s2 += v[i] * v[i];
  }
  #pragma unroll
  for (int off = 32; off > 0; off >>= 1) { s += __shfl_xor(s, off); s2 += __shfl_xor(s2, off); }
  float mean = s / (float)D;
  float var = s2 / (float)D - mean * mean;
  float inv = rsqrtf(var + 1e-5f);
  #pragma unroll
  for (int i = 0; i < NV; ++i) {
    int col = lane + i * 64;
    float y = (v[i] - mean) * inv * w[col] + b[col];
    size_t o = (size_t)row * D + col;
    if (outf) outf[o] = y;
    if (outb) outb[o] = f2bf(y);
  }
}

// ---------------- encoder self-attention: MFMA flash-style, V transposed in-kernel ----------
__global__ __launch_bounds__(256) void attn_enc3_kernel(
    const u16* __restrict__ qkv, u16* __restrict__ out)
{
  __shared__ __align__(16) u16 Ks[128 * 40];
  __shared__ __align__(16) u16 Vt[32 * 136];
  __shared__ __align__(16) u16 Pl[4 * 32 * 136];
  int qt = blockIdx.x, h = blockIdx.y, b = blockIdx.z;
  int t = threadIdx.x, lane = t & 63, w = t >> 6;
  int mrow = lane & 15, quad = lane >> 4;
  int q0 = qt * 128 + w * 32;
  short8 qf[2];
  #pragma unroll
  for (int mi = 0; mi < 2; ++mi)
    qf[mi] = *(const short8*)(qkv + (size_t)(b * CC + q0 + mi * 16 + mrow) * 768 + h * 32 + quad * 8);
  floatx4 o[2][2];
  #pragma unroll
  for (int mi = 0; mi < 2; ++mi)
    #pragma unroll
    for (int di = 0; di < 2; ++di) o[mi][di] = (floatx4){0.f, 0.f, 0.f, 0.f};
  float lst[2][4] = {{0.f,0.f,0.f,0.f},{0.f,0.f,0.f,0.f}};
  const float sc = 0.17677669529663687f * 1.4426950408889634f;
  const floatx4 zf = (floatx4){0.f, 0.f, 0.f, 0.f};
  for (int jt = 0; jt < 4; ++jt) {
    if (jt) __syncthreads();
    #pragma unroll
    for (int rep = 0; rep < 2; ++rep) {  // K tile: 128 j x 32 d
      int j = (t >> 2) + rep * 64;
      int q4 = (t & 3) * 8;
      uint4 kk = *(const uint4*)(qkv + (size_t)(b * CC + jt * 128 + j) * 768 + 256 + h * 32 + q4);
      *(uint4*)&Ks[j * 40 + q4] = kk;
    }
    #pragma unroll
    for (int rep = 0; rep < 2; ++rep) {  // V tile: transpose+permute into Vt[d][jp]
      int jl = (t >> 2) + rep * 64;
      int d0 = (t & 3) * 8;
      uint4 vv = *(const uint4*)(qkv + (size_t)(b * CC + jt * 128 + jl) * 768 + 512 + h * 32 + d0);
      u16 tmp[8]; *(uint4*)tmp = vv;
      int jp = (jl & 15) * 8 + (jl >> 4);
      #pragma unroll
      for (int i = 0; i < 8; ++i) Vt[(d0 + i) * 136 + jp] = tmp[i];
    }
    __syncthreads();
    floatx4 s[2][8];
    #pragma unroll
    for (int nj = 0; nj < 8; ++nj) {
      short8 bf = *(const short8*)&Ks[(nj * 16 + mrow) * 40 + quad * 8];
      s[0][nj] = __builtin_amdgcn_mfma_f32_16x16x32_bf16(qf[0], bf, zf, 0, 0, 0);
      s[1][nj] = __builtin_amdgcn_mfma_f32_16x16x32_bf16(qf[1], bf, zf, 0, 0, 0);
    }
    #pragma unroll
    for (int mi = 0; mi < 2; ++mi) {
      #pragma unroll
      for (int r = 0; r < 4; ++r) {
        float ps = 0.f; u16 hv[8];
        #pragma unroll
        for (int nj = 0; nj < 8; ++nj) {
          float p = exp2f(s[mi][nj][r] * sc);
          ps += p; hv[nj] = f2bf(p);
        }
        lst[mi][r] += ps;
        *(uint4*)&Pl[(w * 32 + mi * 16 + quad * 4 + r) * 136 + mrow * 8] = *(uint4*)hv;
      }
    }
    #pragma unroll
    for (int ks = 0; ks < 4; ++ks) {
      short8 a0 = *(const short8*)&Pl[(w * 32 + mrow) * 136 + ks * 32 + quad * 8];
      short8 a1 = *(const short8*)&Pl[(w * 32 + 16 + mrow) * 136 + ks * 32 + quad * 8];
      short8 b0 = *(const short8*)&Vt[mrow * 136 + ks * 32 + quad * 8];
      short8 b1 = *(const short8*)&Vt[(16 + mrow) * 136 + ks * 32 + quad * 8];
      o[0][0] = __builtin_amdgcn_mfma_f32_16x16x32_bf16(a0, b0, o[0][0], 0, 0, 0);
      o[0][1] = __builtin_amdgcn_mfma_f32_16x16x32_bf16(a0, b1, o[0][1], 0, 0, 0);
      o[1][0] = __builtin_amdgcn_mfma_f32_16x16x32_bf16(a1, b0, o[1][0], 0, 0, 0);
      o[1][1] = __builtin_amdgcn_mfma_f32_16x16x32_bf16(a1, b1, o[1][1], 0, 0, 0);
    }
  }
  #pragma unroll
  for (int mi = 0; mi < 2; ++mi) {
    #pragma unroll
    for (int r = 0; r < 4; ++r) {
      float l = lst[mi][r];
      l += __shfl_xor(l, 1); l += __shfl_xor(l, 2);
      l += __shfl_xor(l, 4); l += __shfl_xor(l, 8);
      float inv = 1.f / l;
      int row = b * CC + q0 + mi * 16 + quad * 4 + r;
      #pragma unroll
      for (int di = 0; di < 2; ++di)
        out[(size_t)row * DD + h * 32 + di * 16 + mrow] = f2bf(o[mi][di][r] * inv);
    }
  }
}

// ---------------- prefix cross-attention: MFMA ----------------
__global__ __launch_bounds__(256) void attn_pref2_kernel(
    const u16* __restrict__ qh, const u16* __restrict__ kb, const u16* __restrict__ vtp,
    u16* __restrict__ out)
{
  __shared__ __align__(16) u16 Pl[4 * 16 * 136];
  __shared__ float Ored[4 * 16 * 128];
  __shared__ float Lred[4 * 16];
  int h = blockIdx.x, b = blockIdx.y;
  int t = threadIdx.x, lane = t & 63, w = t >> 6;
  int mrow = lane & 15, quad = lane >> 4;
  const float sc = 0.08838834764831845f * 1.4426950408889634f;
  const floatx4 zf = (floatx4){0.f, 0.f, 0.f, 0.f};
  short8 qf[4];
  #pragma unroll
  for (int ks = 0; ks < 4; ++ks)
    qf[ks] = *(const short8*)(qh + mrow * HH + h * 128 + ks * 32 + quad * 8);
  const u16* kbase = kb + ((size_t)(b * CC + w * 128)) * 1024 + h * 128;
  floatx4 s[8];
  #pragma unroll
  for (int nj = 0; nj < 8; ++nj) {
    floatx4 a = zf;
    #pragma unroll
    for (int ks = 0; ks < 4; ++ks) {
      short8 kf = *(const short8*)(kbase + (size_t)(nj * 16 + mrow) * 1024 + ks * 32 + quad * 8);
      a = __builtin_amdgcn_mfma_f32_16x16x32_bf16(qf[ks], kf, a, 0, 0, 0);
    }
    s[nj] = a;
  }
  #pragma unroll
  for (int r = 0; r < 4; ++r) {
    float ps = 0.f; u16 hv[8];
    #pragma unroll
    for (int nj = 0; nj < 8; ++nj) {
      float p = exp2f(s[nj][r] * sc);
      ps += p; hv[nj] = f2bf(p);
    }
    ps += __shfl_xor(ps, 1); ps += __shfl_xor(ps, 2);
    ps += __shfl_xor(ps, 4); ps += __shfl_xor(ps, 8);
    if (mrow == 0) Lred[w * 16 + quad * 4 + r] = ps;
    *(uint4*)&Pl[(w * 16 + quad * 4 + r) * 136 + mrow * 8] = *(uint4*)hv;
  }
  short8 pa[4];
  #pragma unroll
  for (int ks = 0; ks < 4; ++ks)
    pa[ks] = *(const short8*)&Pl[(w * 16 + mrow) * 136 + ks * 32 + quad * 8];
  const u16* vbase = vtp + ((size_t)(b * 8 + h) * 128) * 512 + w * 128;
  floatx4 o[8];
  #pragma unroll
  for (int nd = 0; nd < 8; ++nd) o[nd] = zf;
  #pragma unroll
  for (int nd = 0; nd < 8; ++nd) {
    #pragma unroll
    for (int ks = 0; ks < 4; ++ks) {
      short8 vf = *(const short8*)(vbase + (size_t)(nd * 16 + mrow) * 512 + ks * 32 + quad * 8);
      o[nd] = __builtin_amdgcn_mfma_f32_16x16x32_bf16(pa[ks], vf, o[nd], 0, 0, 0);
    }
  }
  #pragma unroll
  for (int nd = 0; nd < 8; ++nd)
    #pragma unroll
    for (int r = 0; r < 4; ++r)
      Ored[(w * 16 + quad * 4 + r) * 128 + nd * 16 + mrow] = o[nd][r];
  __syncthreads();
  int row = t >> 4, d0 = (t & 15) * 8;
  float l = Lred[row] + Lred[16 + row] + Lred[32 + row] + Lred[48 + row];
  float inv = 1.f / l;
  u16 ov[8];
  #pragma unroll
  for (int i = 0; i < 8; ++i) {
    int d = d0 + i;
    float sum = Ored[row * 128 + d] + Ored[(16 + row) * 128 + d]
              + Ored[(32 + row) * 128 + d] + Ored[(48 + row) * 128 + d];
    ov[i] = f2bf(sum * inv);
  }
  *(uint4*)(out + ((size_t)(b * PP + row)) * HH + h * 128 + d0) = *(const uint4*)ov;
}

extern "C" void kernel_launch(void* const* d_in, const int* in_sizes, int n_in,
                              void* d_out, int out_size, void* d_ws, size_t ws_size,
                              hipStream_t stream)
{
  const int* vi = (const int*)d_in[0];
  const int* si = (const int*)d_in[1];
  const int* mk = (const int*)d_in[2];
  const float* ve   = (const float*)d_in[3];
  const float* se   = (const float*)d_in[4];
  const float* lpe  = (const float*)d_in[5];
  const float* cpe  = (const float*)d_in[6];
  const float* eiw  = (const float*)d_in[7];
  const float* eib  = (const float*)d_in[8];
  const float* eow  = (const float*)d_in[9];
  const float* eob  = (const float*)d_in[10];
  const float* f1w  = (const float*)d_in[11];
  const float* f1b  = (const float*)d_in[12];
  const float* f2w  = (const float*)d_in[13];
  const float* f2b  = (const float*)d_in[14];
  const float* n1w  = (const float*)d_in[15];
  const float* n1b  = (const float*)d_in[16];
  const float* n2w  = (const float*)d_in[17];
  const float* n2b  = (const float*)d_in[18];
  const float* tlw  = (const float*)d_in[19];
  const float* tlb  = (const float*)d_in[20];
  const float* thw  = (const float*)d_in[21];
  const float* thb  = (const float*)d_in[22];
  const float* pq   = (const float*)d_in[23];
  const float* paiw = (const float*)d_in[24];
  const float* paib = (const float*)d_in[25];
  const float* paow = (const float*)d_in[26];
  const float* paob = (const float*)d_in[27];
  const float* pnw  = (const float*)d_in[28];
  const float* pnb  = (const float*)d_in[29];

  const int NROW = BB * CC;  // 16384
  const size_t MB = 1048576;
  char* base = (char*)d_ws;
  // encoder phase:
  u16* xb   = (u16*)(base);                // [0,8M)   bf16 residual stream (post-LN)
  u16* qkvb = (u16*)(base + 8 * MB);       // [8M,32M)
  u16* atto = (u16*)(base + 32 * MB);      // [32M,40M)
  u16* h1   = (u16*)(base + 8 * MB);       // [8M,40M) (qkvb/atto dead)
  u16* tln  = (u16*)(base + 96 * MB);      // [96M,104M)
  // final phase:
  u16* ch   = (u16*)(base);                // [0,32M)   (xb/h1 dead)
  u16* kb   = (u16*)(base + 32 * MB);      // [32M,64M)
  u16* vtp  = (u16*)(base + 64 * MB);      // [64M,96M)
  u16* wbf  = (u16*)(base + 104 * MB);     // [104M,~119.8M)
  u16* qh    = (u16*)(base + 120 * MB);
  u16* prefo = qh + 32768;
  float* prefout = (float*)(base + 122 * MB);

  u16* eiw_b  = wbf + 0;
  u16* eow_b  = wbf + 786432;
  u16* f1w_b  = wbf + 1048576;
  u16* f2w_b  = wbf + 2097152;
  u16* thw_b  = wbf + 3145728;
  u16* paiw_b = wbf + 3407872;
  u16* paow_b = wbf + 6553600;
  u16* pqb    = wbf + 7602176;
  u16* veb    = wbf + 7618560;
  u16* seb    = wbf + 7749888;
  u16* lpeb   = wbf + 7750656;
  u16* cpeb   = wbf + 7754752;

  dim3 blk(256);
  cvt_kernel<<<7701, blk, 0, stream>>>(eiw, eow, f1w, f2w, thw, paiw, paow, pq,
                                       ve, se, lpe, cpe, wbf);
  embed_kernel<<<NROW/2, blk, 0, stream>>>(vi, si, mk, veb, seb, lpeb, cpeb, xb);
  for (int i = 0; i < NLAY; ++i) {
    gwide_kernel<384, false, false, false><<<dim3(2, NROW/32), blk, 0, stream>>>(
        xb, eiw_b + (size_t)i*768*DD, eib + i*768, nullptr, nullptr, nullptr, nullptr, nullptr,
        qkvb, 768, DD);
    attn_enc3_kernel<<<dim3(4, 8, BB), blk, 0, stream>>>(qkvb, atto);
    gwide_kernel<256, false, true, false><<<dim3(1, NROW/32), blk, 0, stream>>>(
        atto, eow_b + (size_t)i*DD*DD, eob + i*DD, xb, n1w + i*DD, n1b + i*DD, nullptr, nullptr,
        xb, DD, DD);
    gwide_kernel<256, true, false, false><<<dim3(4, NROW/32), blk, 0, stream>>>(
        xb, f1w_b + (size_t)i*HH*DD, f1b + i*HH, nullptr, nullptr, nullptr, nullptr, nullptr,
        h1, HH, DD);
    if (i < NLAY - 1) {
      gwide_kernel<256, false, true, false><<<dim3(1, NROW/32), blk, 0, stream>>>(
          h1, f2w_b + (size_t)i*DD*HH, f2b + i*DD, xb, n2w + i*DD, n2b + i*DD, nullptr, nullptr,
          xb, DD, HH);
    } else {
      gwide_kernel<256, false, true, true><<<dim3(1, NROW/32), blk, 0, stream>>>(
          h1, f2w_b + (size_t)i*DD*HH, f2b + i*DD, xb, n2w + i*DD, n2b + i*DD, tlw, tlb,
          tln, DD, HH);
    }
  }
  gwide_kernel<256, false, false, false><<<dim3(4, NROW/32), blk, 0, stream>>>(
      tln, thw_b, thb, nullptr, nullptr, nullptr, nullptr, nullptr, ch, HH, DD);
  gemm128s_kernel<<<2056, blk, 0, stream>>>(
      ch, paiw_b + (size_t)HH*HH, paib + HH, kb, vtp,
      pqb, paiw_b, paib, qh, HH);
  attn_pref2_kernel<<<dim3(8, BB), blk, 0, stream>>>(qh, kb, vtp, prefo);
  gemm128_kernel<<<dim3(1024/128, (BB*PP)/128), blk, 0, stream>>>(
      prefo, paow_b, paob, pq, prefout, BB*PP, HH, HH, 2 | 4);
  lnw_kernel<1024><<<(BB*PP)/4, blk, 0, stream>>>(prefout, pnw, pnb, (float*)d_out, nullptr);
}